// Round 3
// baseline (219.169 us; speedup 1.0000x reference)
//
#include <hip/hip_runtime.h>

#define HIDDEN 128
#define LDSW 136   // halves; 272 B row stride: 16B-aligned b128 + canonical 4*lane%32 bank pattern

typedef _Float16 f16;
typedef f16 f16x2 __attribute__((ext_vector_type(2)));
typedef f16 f16x8 __attribute__((ext_vector_type(8)));

static __device__ __forceinline__ float fdot2(f16x2 a, f16x2 b, float c) {
    // v_dot2_f32_f16: fp16 pair dot, fp32 accumulate
    return __builtin_amdgcn_fdot2(a, b, c, false);
}

// wsh_t[j][k] = Wsym[k][j] = w[k][j] + w[j][k]  (col-major Wsym, fp16)
__global__ __launch_bounds__(256) void prep_w(const float* __restrict__ w,
                                              f16* __restrict__ wsh_t) {
    int idx = blockIdx.x * 256 + threadIdx.x;   // 0..16383
    int j = idx >> 7, k = idx & 127;
    wsh_t[idx] = (f16)(w[k * HIDDEN + j] + w[j * HIDDEN + k]);
}

// zh = (f16)z — pure streaming convert, 4 floats/thread
__global__ __launch_bounds__(256) void conv_z(const float* __restrict__ z,
                                              f16* __restrict__ zh, int n4) {
    int idx = blockIdx.x * 256 + threadIdx.x;
    if (idx >= n4) return;
    float4 v = ((const float4*)z)[idx];
    f16x2 h0 = {(f16)v.x, (f16)v.y};
    f16x2 h1 = {(f16)v.z, (f16)v.w};
    ((f16x2*)zh)[2 * idx]     = h0;
    ((f16x2*)zh)[2 * idx + 1] = h1;
}

// uh = (f16)(zh @ Wsym). Block = 256 thr / 64 rows; wave owns 16 rows;
// lane owns cols {lane, lane+64}. W in LDS (b128 reads, conflict-free);
// z read as wave-uniform global broadcast loads — near-zero LDS traffic.
__global__ __launch_bounds__(256) void gemm_reg(const f16* __restrict__ zh,
                                                const f16* __restrict__ wsh_t,
                                                f16* __restrict__ uh, int nrows) {
    __shared__ f16 wlt[HIDDEN * LDSW];   // 34816 B
    int tid = threadIdx.x;
    // Stage W^T: 2048 16B chunks, coalesced reads, aligned b128 LDS writes
    {
        const f16x8* g = (const f16x8*)wsh_t;
        #pragma unroll
        for (int it = 0; it < 8; ++it) {
            int idx = it * 256 + tid;
            int j = idx >> 4, kc = idx & 15;
            *(f16x8*)&wlt[j * LDSW + kc * 8] = g[idx];
        }
    }
    __syncthreads();

    int wave = tid >> 6, lane = tid & 63;
    int row0 = blockIdx.x * 64 + wave * 16;
    if (row0 > nrows - 16) row0 = nrows - 16;   // tail: overlapping identical writes, benign

    const f16* zb = zh + (size_t)row0 * HIDDEN;
    const f16* wc0 = &wlt[lane * LDSW];
    const f16* wc1 = &wlt[(lane + 64) * LDSW];

    float acc0[16], acc1[16];
    #pragma unroll
    for (int r = 0; r < 16; ++r) { acc0[r] = 0.f; acc1[r] = 0.f; }

    for (int kb = 0; kb < 16; ++kb) {           // 8 k per iteration
        f16x8 wa = *(const f16x8*)&wc0[kb * 8];  // ds_read_b128, conflict-free
        f16x8 wb = *(const f16x8*)&wc1[kb * 8];
        f16x8 zv[16];
        #pragma unroll
        for (int r = 0; r < 16; ++r)             // wave-uniform broadcast dwordx4
            zv[r] = *(const f16x8*)&zb[r * HIDDEN + kb * 8];
        const f16x2* wap = (const f16x2*)&wa;
        const f16x2* wbp = (const f16x2*)&wb;
        #pragma unroll
        for (int r = 0; r < 16; ++r) {
            const f16x2* zp = (const f16x2*)&zv[r];
            float a0 = acc0[r], a1 = acc1[r];
            #pragma unroll
            for (int i = 0; i < 4; ++i) {
                a0 = fdot2(zp[i], wap[i], a0);
                a1 = fdot2(zp[i], wbp[i], a1);
            }
            acc0[r] = a0; acc1[r] = a1;
        }
    }

    f16* ub = uh + (size_t)row0 * HIDDEN;
    #pragma unroll
    for (int r = 0; r < 16; ++r) {
        ub[r * HIDDEN + lane]      = (f16)acc0[r];
        ub[r * HIDDEN + lane + 64] = (f16)acc1[r];
    }
}

// out[e] = sigmoid(dot(uh[src[e]], zh[dst[e]])) — 16 lanes/edge, one dwordx4 per side.
__global__ __launch_bounds__(256) void edge_score16(const f16* __restrict__ uh,
                                                    const f16* __restrict__ zh,
                                                    const int* __restrict__ eidx,
                                                    float* __restrict__ out, int E) {
    int tid = threadIdx.x;
    int g = tid >> 4, t = tid & 15;
    int e = blockIdx.x * 16 + g;
    if (e >= E) return;
    int src = eidx[e];
    int dst = eidx[E + e];
    const float4* a4 = (const float4*)(uh + (size_t)src * HIDDEN);
    const float4* b4 = (const float4*)(zh + (size_t)dst * HIDDEN);
    float4 av = a4[t], bv = b4[t];        // 16 lanes x 16 B = full 256 B row, coalesced
    const f16x2* ap = (const f16x2*)&av;
    const f16x2* bp = (const f16x2*)&bv;
    float s = 0.f;
    #pragma unroll
    for (int i = 0; i < 4; ++i) s = fdot2(ap[i], bp[i], s);
    #pragma unroll
    for (int off = 8; off > 0; off >>= 1) s += __shfl_down(s, off, 16);
    if (t == 0) out[e] = 1.0f / (1.0f + __expf(-s));
}

extern "C" void kernel_launch(void* const* d_in, const int* in_sizes, int n_in,
                              void* d_out, int out_size, void* d_ws, size_t ws_size,
                              hipStream_t stream) {
    const float* z    = (const float*)d_in[0];
    const int*   eidx = (const int*)d_in[1];
    const float* w    = (const float*)d_in[2];
    float* out = (float*)d_out;

    int nrows = in_sizes[0] / HIDDEN;   // 100000
    int E = out_size;                    // 1000000
    int n4 = nrows * HIDDEN / 4;         // 3.2M float4 chunks

    f16* wsh_t = (f16*)d_ws;                         // 32 KB
    f16* zh    = wsh_t + HIDDEN * HIDDEN;            // 25.6 MB
    f16* uh    = zh + (size_t)nrows * HIDDEN;        // 25.6 MB

    prep_w<<<(HIDDEN * HIDDEN) / 256, 256, 0, stream>>>(w, wsh_t);
    conv_z<<<(n4 + 255) / 256, 256, 0, stream>>>(z, zh, n4);
    gemm_reg<<<(nrows + 63) / 64, 256, 0, stream>>>(zh, wsh_t, uh, nrows);
    edge_score16<<<(E + 15) / 16, 256, 0, stream>>>(uh, zh, eidx, out, E);
}

// Round 4
// 175.169 us; speedup vs baseline: 1.2512x; 1.2512x over previous
//
#include <hip/hip_runtime.h>

#define HIDDEN 128
#define LDSW 136   // halves; 272 B row stride: 16B-aligned b128, conflict-free (0 conflicts R3)

typedef _Float16 f16;
typedef f16 f16x2 __attribute__((ext_vector_type(2)));
typedef f16 f16x8 __attribute__((ext_vector_type(8)));
typedef float f32x16 __attribute__((ext_vector_type(16)));

static __device__ __forceinline__ float fdot2(f16x2 a, f16x2 b, float c) {
    return __builtin_amdgcn_fdot2(a, b, c, false);   // v_dot2_f32_f16
}

// wsh_t[j][k] = Wsym[k][j] = w[k][j] + w[j][k]  (col-major Wsym, fp16)
__global__ __launch_bounds__(256) void prep_w(const float* __restrict__ w,
                                              f16* __restrict__ wsh_t) {
    int idx = blockIdx.x * 256 + threadIdx.x;   // 0..16383
    int j = idx >> 7, k = idx & 127;
    wsh_t[idx] = (f16)(w[k * HIDDEN + j] + w[j * HIDDEN + k]);
}

// uh = (f16)(z @ Wsym), zh = (f16)z — fused. MFMA 32x32x16_f16.
// Block = 256 thr (4 waves) x 128 rows; wave owns 32 rows x 128 cols (4 acc tiles).
// A: z fp32 from global (coalesced at transaction level), converted in-reg,
//    re-stored as zh. B: W^T fp16 in LDS, b128 frag reads.
__global__ __launch_bounds__(256) void gemm_mfma(const float* __restrict__ z,
                                                 const f16* __restrict__ wsh_t,
                                                 f16* __restrict__ zh,
                                                 f16* __restrict__ uh, int nrows) {
    __shared__ f16 wlt[HIDDEN * LDSW];   // 34816 B
    int tid = threadIdx.x;
    {   // stage W^T: 2048 16B chunks, coalesced
        const f16x8* g = (const f16x8*)wsh_t;
        #pragma unroll
        for (int it = 0; it < 8; ++it) {
            int idx = it * 256 + tid;
            int j = idx >> 4, kc = idx & 15;
            *(f16x8*)&wlt[j * LDSW + kc * 8] = g[idx];
        }
    }
    __syncthreads();

    int wave = tid >> 6, lane = tid & 63;
    int row0 = blockIdx.x * 128 + wave * 32;
    if (row0 > nrows - 32) row0 = nrows - 32;   // tail overlap: identical writes, benign

    int m = lane & 31, half = lane >> 5;        // A: row=m, k=half*8+j ; B: col=m (per tile)
    const float* zr = z  + (size_t)(row0 + m) * HIDDEN + half * 8;
    f16*        zhr = zh + (size_t)(row0 + m) * HIDDEN + half * 8;
    const f16* wbase = &wlt[m * LDSW + half * 8];

    f32x16 acc0 = {0.f}, acc1 = {0.f}, acc2 = {0.f}, acc3 = {0.f};
    #pragma unroll
    for (int r = 0; r < 16; ++r) { acc0[r] = 0.f; acc1[r] = 0.f; acc2[r] = 0.f; acc3[r] = 0.f; }

    #pragma unroll
    for (int ks = 0; ks < 8; ++ks) {            // K = 16 per step
        float4 a0 = *(const float4*)(zr + 16 * ks);
        float4 a1 = *(const float4*)(zr + 16 * ks + 4);
        f16x8 af = {(f16)a0.x, (f16)a0.y, (f16)a0.z, (f16)a0.w,
                    (f16)a1.x, (f16)a1.y, (f16)a1.z, (f16)a1.w};
        *(f16x8*)(zhr + 16 * ks) = af;          // fused zh emit
        f16x8 b0 = *(const f16x8*)(wbase + 16 * ks);
        f16x8 b1 = *(const f16x8*)(wbase + 32 * LDSW + 16 * ks);
        f16x8 b2 = *(const f16x8*)(wbase + 64 * LDSW + 16 * ks);
        f16x8 b3 = *(const f16x8*)(wbase + 96 * LDSW + 16 * ks);
        acc0 = __builtin_amdgcn_mfma_f32_32x32x16_f16(af, b0, acc0, 0, 0, 0);
        acc1 = __builtin_amdgcn_mfma_f32_32x32x16_f16(af, b1, acc1, 0, 0, 0);
        acc2 = __builtin_amdgcn_mfma_f32_32x32x16_f16(af, b2, acc2, 0, 0, 0);
        acc3 = __builtin_amdgcn_mfma_f32_32x32x16_f16(af, b3, acc3, 0, 0, 0);
    }

    // C/D: col = lane&31 (+32c), row = (r&3) + 8*(r>>2) + 4*half   [m74/m101]
    f16* ur = uh + (size_t)row0 * HIDDEN;
    #pragma unroll
    for (int r = 0; r < 16; ++r) {
        int row = (r & 3) + 8 * (r >> 2) + 4 * half;
        f16* p = ur + (size_t)row * HIDDEN + m;
        p[0]  = (f16)acc0[r];
        p[32] = (f16)acc1[r];
        p[64] = (f16)acc2[r];
        p[96] = (f16)acc3[r];
    }
}

// out[e] = sigmoid(dot(uh[src], zh[dst])) — 4 lanes/edge, 8 independent dwordx4/lane (4x MLP).
__global__ __launch_bounds__(256) void edge_score4(const f16* __restrict__ uh,
                                                   const f16* __restrict__ zh,
                                                   const int* __restrict__ eidx,
                                                   float* __restrict__ out, int E) {
    int tid = threadIdx.x;
    int g = tid >> 2, t = tid & 3;
    int e = blockIdx.x * 64 + g;
    if (e >= E) return;
    int src = eidx[e];
    int dst = eidx[E + e];
    const float4* a4 = (const float4*)(uh + (size_t)src * HIDDEN);
    const float4* b4 = (const float4*)(zh + (size_t)dst * HIDDEN);
    float4 av[4], bv[4];
    #pragma unroll
    for (int i = 0; i < 4; ++i) { av[i] = a4[t + 4 * i]; bv[i] = b4[t + 4 * i]; }
    float s = 0.f;
    #pragma unroll
    for (int i = 0; i < 4; ++i) {
        const f16x2* ap = (const f16x2*)&av[i];
        const f16x2* bp = (const f16x2*)&bv[i];
        #pragma unroll
        for (int j = 0; j < 4; ++j) s = fdot2(ap[j], bp[j], s);
    }
    s += __shfl_xor(s, 1);
    s += __shfl_xor(s, 2);
    if (t == 0) out[e] = 1.0f / (1.0f + __expf(-s));
}

extern "C" void kernel_launch(void* const* d_in, const int* in_sizes, int n_in,
                              void* d_out, int out_size, void* d_ws, size_t ws_size,
                              hipStream_t stream) {
    const float* z    = (const float*)d_in[0];
    const int*   eidx = (const int*)d_in[1];
    const float* w    = (const float*)d_in[2];
    float* out = (float*)d_out;

    int nrows = in_sizes[0] / HIDDEN;   // 100000
    int E = out_size;                    // 1000000

    f16* wsh_t = (f16*)d_ws;                         // 32 KB
    f16* zh    = wsh_t + HIDDEN * HIDDEN;            // 25.6 MB
    f16* uh    = zh + (size_t)nrows * HIDDEN;        // 25.6 MB

    prep_w<<<(HIDDEN * HIDDEN) / 256, 256, 0, stream>>>(w, wsh_t);
    gemm_mfma<<<(nrows + 127) / 128, 256, 0, stream>>>(z, wsh_t, zh, uh, nrows);
    edge_score4<<<(E + 63) / 64, 256, 0, stream>>>(uh, zh, eidx, out, E);
}